// Round 9
// baseline (263.865 us; speedup 1.0000x reference)
//
#include <hip/hip_runtime.h>

// ---------------------------------------------------------------------------
// CausalSelfAttention: y = proj(attn(qkv(x)))  B=4 T=2048 E=1024 H=16 D=64
// Mask: rows<512 attend cols<512 (full); rows>=512 causal.
// R15: fix R14's LDS overflow. R14 bug: 8 epilogue stages x 4096 halfs =
//     64KB aliased over a 48KB smem -> waves 6,7 wrote OOB (absmax 0.309).
//     Fix: two-phase epilogue (waves 0-3 then 4-7 reuse the same 32KB of
//     stage slots; uniform __syncthreads between phases). Keeps LDS 48KB ->
//     3 blocks/CU x 8 waves = 24 waves/CU. 128x256 K-loop, swizzles, attn
//     (R11 body + T5), prep, proj unchanged from R14/R13.
// ---------------------------------------------------------------------------

typedef _Float16 f16;
typedef _Float16 f16x4 __attribute__((ext_vector_type(4)));
typedef _Float16 f16x8 __attribute__((ext_vector_type(8)));
typedef float f32x4 __attribute__((ext_vector_type(4)));

#define MFMA16x32(a, b, c) __builtin_amdgcn_mfma_f32_16x16x32_f16(a, b, c, 0, 0, 0)
#define MFMA16x16(a, b, c) __builtin_amdgcn_mfma_f32_16x16x16f16(a, b, c, 0, 0, 0)

__device__ __forceinline__ void gload_lds16(const void* g, void* l) {
  __builtin_amdgcn_global_load_lds(
      (__attribute__((address_space(1))) void*)g,
      (__attribute__((address_space(3))) void*)l, 16, 0, 0);
}

// --------------------------- prep: cast + transposes (one launch) ----------

__global__ __launch_bounds__(256) void k_prep(
    const float* __restrict__ x, f16* __restrict__ xh,
    const float* __restrict__ Wq, f16* __restrict__ Wqt,
    const float* __restrict__ Wp, f16* __restrict__ Wpt) {
  __shared__ float tile[32][33];
  const int bid = blockIdx.x;
  if (bid < 8192) {
    int i = bid * 256 + threadIdx.x;
    float4 v = ((const float4*)x)[i];
    f16x4 o = {(f16)v.x, (f16)v.y, (f16)v.z, (f16)v.w};
    ((f16x4*)xh)[i] = o;
    return;
  }
  const float* W;
  f16* Wt;
  int Ndim, bx, by;
  if (bid < 8192 + 3072) {
    int r = bid - 8192;
    W = Wq; Wt = Wqt; Ndim = 3072; bx = r % 96; by = r / 96;
  } else {
    int r = bid - 11264;
    W = Wp; Wt = Wpt; Ndim = 1024; bx = r % 32; by = r / 32;
  }
  const int tx = threadIdx.x & 31, ty = threadIdx.x >> 5;
  const int n = bx * 32 + tx;
  const int k0 = by * 32;
  for (int j = ty; j < 32; j += 8)
    tile[j][tx] = W[(size_t)(k0 + j) * Ndim + n];
  __syncthreads();
  const int k = k0 + tx;
  for (int j = ty; j < 32; j += 8)
    Wt[(size_t)(bx * 32 + j) * 1024 + k] = (f16)tile[tx][j];
}

// --------------------------- GEMM1: x @ W_qkv -------------------------------
// A [8192][1024] f16, Bt [3072][1024] f16 (W^T). 8 waves, 128x256 tile,
// BK=64. LDS As[128][64] + Bs[256][64] = 48KB (3 blocks/CU = grid).
// Source-side XOR pre-swizzle, linear LDS dest, swizzled fragment reads.
// Two-phase per-wave 64x64 epilogue stage aliased over smem (32KB slots,
// waves 0-3 then 4-7) -> b128 stores to Q[bh][t][d], K[bh][t][d], Vt[bh][d][t].

__global__ __launch_bounds__(512) void k_gemm_qkv(
    const f16* __restrict__ A, const f16* __restrict__ Bt,
    const float* __restrict__ bias,
    f16* __restrict__ Qo, f16* __restrict__ Ko, f16* __restrict__ Vo) {
  constexpr int KD = 1024;
  __shared__ __align__(16) f16 smem[(128 + 256) * 64];  // As | Bs; Es aliased
  f16* As = smem;
  f16* Bs = smem + 128 * 64;
  const int tid = threadIdx.x;
  const int wave = tid >> 6, lane = tid & 63;
  const int g = lane >> 4, l16 = lane & 15;
  const int m0 = blockIdx.y * 128, n0 = blockIdx.x * 256;
  const int wm = (wave >> 2) * 64, wn = (wave & 3) * 64;
  const int srow = wave * 8 + (lane >> 3);          // staging row in 64-group
  const int skc = ((lane & 7) ^ (lane >> 3)) * 8;   // pre-swizzled src chunk

  f32x4 acc[4][4] = {};

  for (int k0 = 0; k0 < KD; k0 += 64) {
    __syncthreads();
    // A: 128 rows in 2 issues of 64; B: 256 rows in 4 issues of 64.
    for (int it = 0; it < 2; ++it)
      gload_lds16(A + (size_t)(m0 + it * 64 + srow) * KD + k0 + skc,
                  As + (it * 64 + wave * 8) * 64);
    for (int it = 0; it < 4; ++it)
      gload_lds16(Bt + (size_t)(n0 + it * 64 + srow) * KD + k0 + skc,
                  Bs + (it * 64 + wave * 8) * 64);
    __syncthreads();
    for (int kk = 0; kk < 64; kk += 32) {
      const int ks = kk >> 3;  // chunk slot base: 0 or 4
      f16x8 af[4], bf[4];
      for (int mi = 0; mi < 4; ++mi) {
        int R = wm + mi * 16 + l16, sw = R & 7;
        af[mi] = *(const f16x8*)(As + R * 64 + ((ks + g) ^ sw) * 8);
      }
      for (int ni = 0; ni < 4; ++ni) {
        int R = wn + ni * 16 + l16, sw = R & 7;
        bf[ni] = *(const f16x8*)(Bs + R * 64 + ((ks + g) ^ sw) * 8);
      }
      for (int mi = 0; mi < 4; ++mi)
        for (int ni = 0; ni < 4; ++ni)
          acc[mi][ni] = MFMA16x32(af[mi], bf[ni], acc[mi][ni]);
    }
  }

  // ---- epilogue: two-phase per-wave 64x64 swizzled stage (aliased) ----
  const int nsub = n0 + wn;            // multiple of 64 -> one (part, head)
  const int part = nsub >> 10;         // 0=Q 1=K 2=V
  const int h    = (nsub >> 6) & 15;
  const int mg   = m0 + wm;
  const int b    = mg >> 11;
  const int tb   = mg & 2047;
  const size_t bh = (size_t)(b * 16 + h);

  float bv[4];
  for (int ni = 0; ni < 4; ++ni) bv[ni] = bias[nsub + ni * 16 + l16];

  __syncthreads();  // all fragment reads of As/Bs complete before overwrite
  f16* Es = smem + (wave & 3) * 4096;  // 64x64 slot, chunk-XOR swizzled
  const int rrow = lane >> 3, rj = lane & 7;

  for (int phase = 0; phase < 2; ++phase) {
    if ((wave >> 2) == phase) {
      for (int mi = 0; mi < 4; ++mi)
        for (int ni = 0; ni < 4; ++ni)
          for (int r = 0; r < 4; ++r) {
            f16 hv = (f16)(acc[mi][ni][r] + bv[ni]);
            int mrow = mi * 16 + g * 4 + r, ncol = ni * 16 + l16;
            if (part == 2)  // store transposed: [d][t]
              Es[ncol * 64 + (mrow ^ ((ncol & 7) << 3))] = hv;
            else            // [t][d]
              Es[mrow * 64 + (ncol ^ ((mrow & 7) << 3))] = hv;
          }
      // same-wave DS write->read: LDS pipe in-order, no barrier needed
      for (int p = 0; p < 8; ++p) {
        int row = p * 8 + rrow;
        f16x8 vv = *(const f16x8*)(Es + row * 64 + (rj ^ (row & 7)) * 8);
        int rcol = rj * 8;
        if (part == 0)
          *(f16x8*)(Qo + (bh * 2048 + tb + row) * 64 + rcol) = vv;
        else if (part == 1)
          *(f16x8*)(Ko + (bh * 2048 + tb + row) * 64 + rcol) = vv;
        else  // row is d, rcol is t-offset
          *(f16x8*)(Vo + (bh * 64 + row) * 2048 + tb + rcol) = vv;
      }
    }
    __syncthreads();  // uniform: phase-0 slot reads done before phase-1 writes
  }
}

// --------------------------- flash attention (1 q-tile / block) -------------
// grid (64 bh, 16 qt-slots); block 256 = 4 waves; wave owns 32 q-rows.
// qt = 15 - blockIdx.y (heavy tiles dispatch first). Block owns the full
// K-range of its q-tile (nt = qt<4 ? 8 : 2(qt+1) k-tiles): fixed-max softmax,
// rsum in-wave -> normalize in-register -> direct f16 Y stores. LDS 33KB ->
// 4 blocks/CU. T5 setprio around MFMA clusters.

__global__ __launch_bounds__(256, 4) void k_attn(
    const f16* __restrict__ Q, const f16* __restrict__ Kb,
    const f16* __restrict__ Vt, f16* __restrict__ Y) {
  __shared__ __align__(16) f16 Ks[2][64 * 64];
  __shared__ __align__(16) f16 Vs[2][64 * 64];
  __shared__ float rs[4 * 32];  // per-wave row sums

  const int tid = threadIdx.x;
  const int wave = tid >> 6, lane = tid & 63;
  const int g = lane >> 4, l16 = lane & 15;
  const int bh = blockIdx.x;
  const int b = bh >> 4, h = bh & 15;
  const int qt = 15 - blockIdx.y;
  const int q0 = qt * 128;
  const int nt = (qt < 4) ? 8 : (qt + 1) * 2;  // k-tiles for this q-tile
  const int srowrel = lane >> 3;
  const int sc = (lane & 7) ^ srowrel;  // XOR-swizzled staging chunk

  const f32x4 sinit = {-8.65617025f, -8.65617025f, -8.65617025f, -8.65617025f};

  // Q B-fragments (operand-swapped QK), pre-scaled by log2(e)/8
  f16x8 aq[2][2];
  for (int mi = 0; mi < 2; ++mi) {
    const f16* qrow =
        Q + ((size_t)bh * 2048 + q0 + wave * 32 + mi * 16 + l16) * 64 + g * 8;
    aq[mi][0] = *(const f16x8*)(qrow);
    aq[mi][1] = *(const f16x8*)(qrow + 32);
    for (int kb = 0; kb < 2; ++kb)
      aq[mi][kb] = aq[mi][kb] * (f16)0.18033688f;
  }

  f32x4 o[2][4] = {};       // o[mi][db]: O[m=g*4+r][d=db*16+l16]
  float rsum[2] = {};       // per-lane partial for row m=l16 (quad's k share)

  // prologue: stage tile 0 into buf 0 (each wave: 16 K rows + 16 V rows)
  for (int it = 0; it < 2; ++it) {
    int row = it * 32 + wave * 8 + srowrel;
    gload_lds16(Kb + ((size_t)bh * 2048 + row) * 64 + sc * 8,
                &Ks[0][(it * 32 + wave * 8) * 64]);
    gload_lds16(Vt + ((size_t)bh * 64 + row) * 2048 + sc * 8,
                &Vs[0][(it * 32 + wave * 8) * 64]);
  }
  __syncthreads();

  int cur = 0;
  for (int i = 0; i < nt; ++i) {
    // ---- stage tile i+1 into buf cur^1 (readers joined at barrier i-1) ----
    if (i + 1 < nt) {
      const int kn0 = (i + 1) << 6;
      for (int it = 0; it < 2; ++it) {
        int row = it * 32 + wave * 8 + srowrel;
        gload_lds16(Kb + ((size_t)bh * 2048 + kn0 + row) * 64 + sc * 8,
                    &Ks[cur ^ 1][(it * 32 + wave * 8) * 64]);
        gload_lds16(Vt + ((size_t)bh * 64 + row) * 2048 + kn0 + sc * 8,
                    &Vs[cur ^ 1][(it * 32 + wave * 8) * 64]);
      }
    }

    // ---- compute tile i from buf cur ----
    const int kt0 = i << 6;
    const f16* Kc = Ks[cur];
    const f16* Vc = Vs[cur];

    // T = K Q^T : T[k=g*4+r][m=l16] per nb (k-block), mi (q-block)
    f32x4 t[2][4];
    __builtin_amdgcn_s_setprio(1);
    for (int nb = 0; nb < 4; ++nb) {
      int R = nb * 16 + l16, sw = R & 7;
      f16x8 bk0 = *(const f16x8*)(Kc + R * 64 + ((0 + g) ^ sw) * 8);
      f16x8 bk1 = *(const f16x8*)(Kc + R * 64 + ((4 + g) ^ sw) * 8);
      for (int mi = 0; mi < 2; ++mi) {
        f32x4 acc = MFMA16x32(bk0, aq[mi][0], sinit);
        t[mi][nb] = MFMA16x32(bk1, aq[mi][1], acc);
      }
    }
    __builtin_amdgcn_s_setprio(0);

    // exp -> P stays in registers as 16x16x16 A-frags ap[nb][mi]
    const bool masked = (q0 >= 512) && (kt0 >= q0);
    f16x4 ap[4][2];
    for (int mi = 0; mi < 2; ++mi) {
      const int mrow = q0 + wave * 32 + mi * 16 + l16;
      for (int nb = 0; nb < 4; ++nb)
        for (int r = 0; r < 4; ++r) {
          float pv = __builtin_amdgcn_exp2f(t[mi][nb][r]);
          if (masked && (kt0 + nb * 16 + g * 4 + r > mrow)) pv = 0.f;
          rsum[mi] += pv;
          ap[nb][mi][r] = (f16)pv;
        }
    }

    // O += P V : A = ap (in-register), B = V^T b64 frags from LDS
    __builtin_amdgcn_s_setprio(1);
    for (int db = 0; db < 4; ++db)
      for (int nb = 0; nb < 4; ++nb) {
        int R = db * 16 + l16, sw = R & 7;
        int c = nb * 2 + (g >> 1);
        f16x4 bv = *(const f16x4*)(Vc + R * 64 + (c ^ sw) * 8 + (g & 1) * 4);
        for (int mi = 0; mi < 2; ++mi)
          o[mi][db] = MFMA16x16(ap[nb][mi], bv, o[mi][db]);
      }
    __builtin_amdgcn_s_setprio(0);

    __syncthreads();  // joins all waves' reads of buf cur + drains stages
    cur ^= 1;
  }

  // reduce rsum across quads: all lanes with same l16 get the row total
  for (int mi = 0; mi < 2; ++mi) {
    rsum[mi] += __shfl_xor(rsum[mi], 16, 64);
    rsum[mi] += __shfl_xor(rsum[mi], 32, 64);
  }

  // broadcast row totals to the lanes that hold O rows g*4+r (via LDS)
  if (g == 0)
    for (int mi = 0; mi < 2; ++mi) rs[wave * 32 + mi * 16 + l16] = rsum[mi];
  // same-wave DS write->read: LDS pipe in-order, no barrier needed
  float rinv[2][4];
  for (int mi = 0; mi < 2; ++mi)
    for (int r = 0; r < 4; ++r)
      rinv[mi][r] = 1.0f / rs[wave * 32 + mi * 16 + g * 4 + r];

  // normalize -> f16 -> direct stores (no LDS stage; L2 merges 32B segments)
  const size_t ybase = (size_t)b * 2048 + q0 + wave * 32;
  for (int mi = 0; mi < 2; ++mi)
    for (int db = 0; db < 4; ++db)
      for (int r = 0; r < 4; ++r)
        Y[(ybase + mi * 16 + g * 4 + r) * 1024 + h * 64 + db * 16 + l16] =
            (f16)(o[mi][db][r] * rinv[mi][r]);
}

// --------------------------- GEMM2: y @ W_proj ------------------------------

__global__ __launch_bounds__(256) void k_gemm_proj(
    const f16* __restrict__ A, const f16* __restrict__ Bt,
    const float* __restrict__ bias, float* __restrict__ out) {
  constexpr int KD = 1024;
  __shared__ __align__(16) f16 As[128 * 64];
  __shared__ __align__(16) f16 Bs[128 * 64];
  const int tid = threadIdx.x;
  const int wave = tid >> 6, lane = tid & 63;
  const int g = lane >> 4, l16 = lane & 15;
  const int m0 = blockIdx.y * 128, n0 = blockIdx.x * 128;
  const int wm = (wave >> 1) * 64, wn = (wave & 1) * 64;
  const int srow = wave * 8 + (lane >> 3);
  const int skc = ((lane & 7) ^ (lane >> 3)) * 8;   // pre-swizzled src chunk

  f32x4 acc[4][4] = {};

  for (int k0 = 0; k0 < KD; k0 += 64) {
    __syncthreads();
    for (int it = 0; it < 4; ++it) {
      gload_lds16(A + (size_t)(m0 + it * 32 + srow) * KD + k0 + skc,
                  As + (it * 32 + wave * 8) * 64);
      gload_lds16(Bt + (size_t)(n0 + it * 32 + srow) * KD + k0 + skc,
                  Bs + (it * 32 + wave * 8) * 64);
    }
    __syncthreads();
    for (int kk = 0; kk < 64; kk += 32) {
      const int ks = kk >> 3;
      f16x8 af[4], bf[4];
      for (int mi = 0; mi < 4; ++mi) {
        int R = wm + mi * 16 + l16, sw = R & 7;
        af[mi] = *(const f16x8*)(As + R * 64 + ((ks + g) ^ sw) * 8);
      }
      for (int ni = 0; ni < 4; ++ni) {
        int R = wn + ni * 16 + l16, sw = R & 7;
        bf[ni] = *(const f16x8*)(Bs + R * 64 + ((ks + g) ^ sw) * 8);
      }
      for (int mi = 0; mi < 4; ++mi)
        for (int ni = 0; ni < 4; ++ni)
          acc[mi][ni] = MFMA16x32(af[mi], bf[ni], acc[mi][ni]);
    }
  }

  float bv[4];
  for (int ni = 0; ni < 4; ++ni) bv[ni] = bias[n0 + wn + ni * 16 + l16];

  for (int mi = 0; mi < 4; ++mi)
    for (int ni = 0; ni < 4; ++ni)
      for (int r = 0; r < 4; ++r) {
        int m = m0 + wm + mi * 16 + g * 4 + r;
        int n = n0 + wn + ni * 16 + l16;
        out[(size_t)m * 1024 + n] = acc[mi][ni][r] + bv[ni];
      }
}

// --------------------------- launch ----------------------------------------

extern "C" void kernel_launch(void* const* d_in, const int* in_sizes, int n_in,
                              void* d_out, int out_size, void* d_ws,
                              size_t ws_size, hipStream_t stream) {
  const float* x      = (const float*)d_in[0];
  const float* W_qkv  = (const float*)d_in[1];
  const float* b_qkv  = (const float*)d_in[2];
  const float* W_proj = (const float*)d_in[3];
  const float* b_proj = (const float*)d_in[4];
  float* out = (float*)d_out;

  char* ws = (char*)d_ws;
  f16* xh    = (f16*)ws;   ws += (size_t)8192 * 1024 * 2;   // also reused as Y
  f16* Wqt   = (f16*)ws;   ws += (size_t)3072 * 1024 * 2;
  f16* Wpt   = (f16*)ws;   ws += (size_t)1024 * 1024 * 2;
  f16* Qb    = (f16*)ws;   ws += (size_t)64 * 2048 * 64 * 2;
  f16* Kb    = (f16*)ws;   ws += (size_t)64 * 2048 * 64 * 2;
  f16* Vt    = (f16*)ws;   ws += (size_t)64 * 64 * 2048 * 2;
  f16* Y = xh;  // xh fully consumed by k_gemm_qkv before k_attn writes Y

  k_prep<<<12288, 256, 0, stream>>>(x, xh, W_qkv, Wqt, W_proj, Wpt);
  k_gemm_qkv<<<dim3(12, 64), 512, 0, stream>>>(xh, Wqt, b_qkv, Qb, Kb, Vt);
  k_attn<<<dim3(64, 16), 256, 0, stream>>>(Qb, Kb, Vt, Y);
  k_gemm_proj<<<dim3(8, 64), 256, 0, stream>>>(Y, Wpt, b_proj, out);
}

// Round 10
// 256.872 us; speedup vs baseline: 1.0272x; 1.0272x over previous
//
#include <hip/hip_runtime.h>

// ---------------------------------------------------------------------------
// CausalSelfAttention: y = proj(attn(qkv(x)))  B=4 T=2048 E=1024 H=16 D=64
// Mask: rows<512 attend cols<512 (full); rows>=512 causal.
// R16: revert qkv to R13's 4-wave 128x128 (R15's 128x256: VGPR 128 -> only
//     16 waves/CU resident, MfmaUtil 22, 92us; 3rd occupancy-vs-efficiency
//     loss in this family -- structure is a local optimum, stop gambling it).
//     New: attn slot->qt table balances per-CU tile sums. Round-robin gives
//     CU group s slots {s,s+4,s+8,s+12}; old qt=15-slot -> sums {80,74,68,62}
//     (makespan 80, mean 71). New table -> {72,72,72,68}: -10% makespan.
//     attn body (R11 + T5 setprio), prep, proj unchanged.
// ---------------------------------------------------------------------------

typedef _Float16 f16;
typedef _Float16 f16x4 __attribute__((ext_vector_type(4)));
typedef _Float16 f16x8 __attribute__((ext_vector_type(8)));
typedef float f32x4 __attribute__((ext_vector_type(4)));

#define MFMA16x32(a, b, c) __builtin_amdgcn_mfma_f32_16x16x32_f16(a, b, c, 0, 0, 0)
#define MFMA16x16(a, b, c) __builtin_amdgcn_mfma_f32_16x16x16f16(a, b, c, 0, 0, 0)

__device__ __forceinline__ void gload_lds16(const void* g, void* l) {
  __builtin_amdgcn_global_load_lds(
      (__attribute__((address_space(1))) void*)g,
      (__attribute__((address_space(3))) void*)l, 16, 0, 0);
}

// --------------------------- prep: cast + transposes (one launch) ----------

__global__ __launch_bounds__(256) void k_prep(
    const float* __restrict__ x, f16* __restrict__ xh,
    const float* __restrict__ Wq, f16* __restrict__ Wqt,
    const float* __restrict__ Wp, f16* __restrict__ Wpt) {
  __shared__ float tile[32][33];
  const int bid = blockIdx.x;
  if (bid < 8192) {
    int i = bid * 256 + threadIdx.x;
    float4 v = ((const float4*)x)[i];
    f16x4 o = {(f16)v.x, (f16)v.y, (f16)v.z, (f16)v.w};
    ((f16x4*)xh)[i] = o;
    return;
  }
  const float* W;
  f16* Wt;
  int Ndim, bx, by;
  if (bid < 8192 + 3072) {
    int r = bid - 8192;
    W = Wq; Wt = Wqt; Ndim = 3072; bx = r % 96; by = r / 96;
  } else {
    int r = bid - 11264;
    W = Wp; Wt = Wpt; Ndim = 1024; bx = r % 32; by = r / 32;
  }
  const int tx = threadIdx.x & 31, ty = threadIdx.x >> 5;
  const int n = bx * 32 + tx;
  const int k0 = by * 32;
  for (int j = ty; j < 32; j += 8)
    tile[j][tx] = W[(size_t)(k0 + j) * Ndim + n];
  __syncthreads();
  const int k = k0 + tx;
  for (int j = ty; j < 32; j += 8)
    Wt[(size_t)(bx * 32 + j) * 1024 + k] = (f16)tile[tx][j];
}

// --------------------------- GEMM1: x @ W_qkv -------------------------------
// A [8192][1024] f16, Bt [3072][1024] f16 (W^T). BK=64, LDS 2x[128][64],
// XOR-swizzled (source-side pre-swizzle, linear LDS dest, swizzled reads).
// Epilogue reuses As/Bs as per-wave 64x64 XOR-swizzled stage -> b128 stores
// to Q[bh][t][d], K[bh][t][d], Vt[bh][d][t].  (R13 version, verified 80.3us.)

__global__ __launch_bounds__(256) void k_gemm_qkv(
    const f16* __restrict__ A, const f16* __restrict__ Bt,
    const float* __restrict__ bias,
    f16* __restrict__ Qo, f16* __restrict__ Ko, f16* __restrict__ Vo) {
  constexpr int KD = 1024;
  __shared__ __align__(16) f16 smem[2 * 128 * 64];  // As | Bs; Es aliased
  f16* As = smem;
  f16* Bs = smem + 128 * 64;
  const int tid = threadIdx.x;
  const int wave = tid >> 6, lane = tid & 63;
  const int g = lane >> 4, l16 = lane & 15;
  const int m0 = blockIdx.y * 128, n0 = blockIdx.x * 128;
  const int wm = (wave >> 1) * 64, wn = (wave & 1) * 64;
  const int srow = wave * 8 + (lane >> 3);          // staging row in 32-group
  const int skc = ((lane & 7) ^ (lane >> 3)) * 8;   // pre-swizzled src chunk

  f32x4 acc[4][4] = {};

  for (int k0 = 0; k0 < KD; k0 += 64) {
    __syncthreads();
    for (int it = 0; it < 4; ++it) {
      gload_lds16(A + (size_t)(m0 + it * 32 + srow) * KD + k0 + skc,
                  As + (it * 32 + wave * 8) * 64);
      gload_lds16(Bt + (size_t)(n0 + it * 32 + srow) * KD + k0 + skc,
                  Bs + (it * 32 + wave * 8) * 64);
    }
    __syncthreads();
    for (int kk = 0; kk < 64; kk += 32) {
      const int ks = kk >> 3;  // chunk slot base: 0 or 4
      f16x8 af[4], bf[4];
      for (int mi = 0; mi < 4; ++mi) {
        int R = wm + mi * 16 + l16, sw = R & 7;
        af[mi] = *(const f16x8*)(As + R * 64 + ((ks + g) ^ sw) * 8);
      }
      for (int ni = 0; ni < 4; ++ni) {
        int R = wn + ni * 16 + l16, sw = R & 7;
        bf[ni] = *(const f16x8*)(Bs + R * 64 + ((ks + g) ^ sw) * 8);
      }
      for (int mi = 0; mi < 4; ++mi)
        for (int ni = 0; ni < 4; ++ni)
          acc[mi][ni] = MFMA16x32(af[mi], bf[ni], acc[mi][ni]);
    }
  }

  // ---- epilogue: per-wave 64x64 swizzled stage (aliased over As/Bs) ----
  const int nsub = n0 + wn;            // multiple of 64 -> one (part, head)
  const int part = nsub >> 10;         // 0=Q 1=K 2=V
  const int h    = (nsub >> 6) & 15;
  const int mg   = m0 + wm;
  const int b    = mg >> 11;
  const int tb   = mg & 2047;
  const size_t bh = (size_t)(b * 16 + h);

  float bv[4];
  for (int ni = 0; ni < 4; ++ni) bv[ni] = bias[nsub + ni * 16 + l16];

  __syncthreads();  // all fragment reads of As/Bs complete before overwrite
  f16* Es = smem + wave * 4096;  // 64x64, chunk-XOR swizzled by row&7

  for (int mi = 0; mi < 4; ++mi)
    for (int ni = 0; ni < 4; ++ni)
      for (int r = 0; r < 4; ++r) {
        f16 hv = (f16)(acc[mi][ni][r] + bv[ni]);
        int mrow = mi * 16 + g * 4 + r, ncol = ni * 16 + l16;
        if (part == 2)  // store transposed: [d][t]
          Es[ncol * 64 + (mrow ^ ((ncol & 7) << 3))] = hv;
        else            // [t][d]
          Es[mrow * 64 + (ncol ^ ((mrow & 7) << 3))] = hv;
      }
  // same-wave DS write->read: LDS pipe in-order, no barrier needed

  const int rrow = lane >> 3, rj = lane & 7;
  for (int p = 0; p < 8; ++p) {
    int row = p * 8 + rrow;
    f16x8 vv = *(const f16x8*)(Es + row * 64 + (rj ^ (row & 7)) * 8);
    int rcol = rj * 8;
    if (part == 0)
      *(f16x8*)(Qo + (bh * 2048 + tb + row) * 64 + rcol) = vv;
    else if (part == 1)
      *(f16x8*)(Ko + (bh * 2048 + tb + row) * 64 + rcol) = vv;
    else  // row is d, rcol is t-offset
      *(f16x8*)(Vo + (bh * 64 + row) * 2048 + tb + rcol) = vv;
  }
}

// --------------------------- flash attention (1 q-tile / block) -------------
// grid (64 bh, 16 qt-slots); block 256 = 4 waves; wave owns 32 q-rows.
// Slot->qt table: under round-robin dispatch CU group s = slots
// {s,s+4,s+8,s+12}; table packs tile sums to {72,72,72,68} (old 80/74/68/62).
// Block owns full K-range of its q-tile (nt = qt<4 ? 8 : 2(qt+1)): fixed-max
// softmax, rsum in-wave -> normalize in-register -> direct f16 Y stores.
// LDS 33KB -> 4 blocks/CU. T5 setprio around MFMA clusters.

__constant__ unsigned char cQT[16] = {15, 14, 13, 9, 11, 12, 10, 8,
                                      0,  2,  4,  7, 1,  3,  5,  6};

__global__ __launch_bounds__(256, 4) void k_attn(
    const f16* __restrict__ Q, const f16* __restrict__ Kb,
    const f16* __restrict__ Vt, f16* __restrict__ Y) {
  __shared__ __align__(16) f16 Ks[2][64 * 64];
  __shared__ __align__(16) f16 Vs[2][64 * 64];
  __shared__ float rs[4 * 32];  // per-wave row sums

  const int tid = threadIdx.x;
  const int wave = tid >> 6, lane = tid & 63;
  const int g = lane >> 4, l16 = lane & 15;
  const int bh = blockIdx.x;
  const int b = bh >> 4, h = bh & 15;
  const int qt = cQT[blockIdx.y];
  const int q0 = qt * 128;
  const int nt = (qt < 4) ? 8 : (qt + 1) * 2;  // k-tiles for this q-tile
  const int srowrel = lane >> 3;
  const int sc = (lane & 7) ^ srowrel;  // XOR-swizzled staging chunk

  const f32x4 sinit = {-8.65617025f, -8.65617025f, -8.65617025f, -8.65617025f};

  // Q B-fragments (operand-swapped QK), pre-scaled by log2(e)/8
  f16x8 aq[2][2];
  for (int mi = 0; mi < 2; ++mi) {
    const f16* qrow =
        Q + ((size_t)bh * 2048 + q0 + wave * 32 + mi * 16 + l16) * 64 + g * 8;
    aq[mi][0] = *(const f16x8*)(qrow);
    aq[mi][1] = *(const f16x8*)(qrow + 32);
    for (int kb = 0; kb < 2; ++kb)
      aq[mi][kb] = aq[mi][kb] * (f16)0.18033688f;
  }

  f32x4 o[2][4] = {};       // o[mi][db]: O[m=g*4+r][d=db*16+l16]
  float rsum[2] = {};       // per-lane partial for row m=l16 (quad's k share)

  // prologue: stage tile 0 into buf 0 (each wave: 16 K rows + 16 V rows)
  for (int it = 0; it < 2; ++it) {
    int row = it * 32 + wave * 8 + srowrel;
    gload_lds16(Kb + ((size_t)bh * 2048 + row) * 64 + sc * 8,
                &Ks[0][(it * 32 + wave * 8) * 64]);
    gload_lds16(Vt + ((size_t)bh * 64 + row) * 2048 + sc * 8,
                &Vs[0][(it * 32 + wave * 8) * 64]);
  }
  __syncthreads();

  int cur = 0;
  for (int i = 0; i < nt; ++i) {
    // ---- stage tile i+1 into buf cur^1 (readers joined at barrier i-1) ----
    if (i + 1 < nt) {
      const int kn0 = (i + 1) << 6;
      for (int it = 0; it < 2; ++it) {
        int row = it * 32 + wave * 8 + srowrel;
        gload_lds16(Kb + ((size_t)bh * 2048 + kn0 + row) * 64 + sc * 8,
                    &Ks[cur ^ 1][(it * 32 + wave * 8) * 64]);
        gload_lds16(Vt + ((size_t)bh * 64 + row) * 2048 + kn0 + sc * 8,
                    &Vs[cur ^ 1][(it * 32 + wave * 8) * 64]);
      }
    }

    // ---- compute tile i from buf cur ----
    const int kt0 = i << 6;
    const f16* Kc = Ks[cur];
    const f16* Vc = Vs[cur];

    // T = K Q^T : T[k=g*4+r][m=l16] per nb (k-block), mi (q-block)
    f32x4 t[2][4];
    __builtin_amdgcn_s_setprio(1);
    for (int nb = 0; nb < 4; ++nb) {
      int R = nb * 16 + l16, sw = R & 7;
      f16x8 bk0 = *(const f16x8*)(Kc + R * 64 + ((0 + g) ^ sw) * 8);
      f16x8 bk1 = *(const f16x8*)(Kc + R * 64 + ((4 + g) ^ sw) * 8);
      for (int mi = 0; mi < 2; ++mi) {
        f32x4 acc = MFMA16x32(bk0, aq[mi][0], sinit);
        t[mi][nb] = MFMA16x32(bk1, aq[mi][1], acc);
      }
    }
    __builtin_amdgcn_s_setprio(0);

    // exp -> P stays in registers as 16x16x16 A-frags ap[nb][mi]
    const bool masked = (q0 >= 512) && (kt0 >= q0);
    f16x4 ap[4][2];
    for (int mi = 0; mi < 2; ++mi) {
      const int mrow = q0 + wave * 32 + mi * 16 + l16;
      for (int nb = 0; nb < 4; ++nb)
        for (int r = 0; r < 4; ++r) {
          float pv = __builtin_amdgcn_exp2f(t[mi][nb][r]);
          if (masked && (kt0 + nb * 16 + g * 4 + r > mrow)) pv = 0.f;
          rsum[mi] += pv;
          ap[nb][mi][r] = (f16)pv;
        }
    }

    // O += P V : A = ap (in-register), B = V^T b64 frags from LDS
    __builtin_amdgcn_s_setprio(1);
    for (int db = 0; db < 4; ++db)
      for (int nb = 0; nb < 4; ++nb) {
        int R = db * 16 + l16, sw = R & 7;
        int c = nb * 2 + (g >> 1);
        f16x4 bv = *(const f16x4*)(Vc + R * 64 + (c ^ sw) * 8 + (g & 1) * 4);
        for (int mi = 0; mi < 2; ++mi)
          o[mi][db] = MFMA16x16(ap[nb][mi], bv, o[mi][db]);
      }
    __builtin_amdgcn_s_setprio(0);

    __syncthreads();  // joins all waves' reads of buf cur + drains stages
    cur ^= 1;
  }

  // reduce rsum across quads: all lanes with same l16 get the row total
  for (int mi = 0; mi < 2; ++mi) {
    rsum[mi] += __shfl_xor(rsum[mi], 16, 64);
    rsum[mi] += __shfl_xor(rsum[mi], 32, 64);
  }

  // broadcast row totals to the lanes that hold O rows g*4+r (via LDS)
  if (g == 0)
    for (int mi = 0; mi < 2; ++mi) rs[wave * 32 + mi * 16 + l16] = rsum[mi];
  // same-wave DS write->read: LDS pipe in-order, no barrier needed
  float rinv[2][4];
  for (int mi = 0; mi < 2; ++mi)
    for (int r = 0; r < 4; ++r)
      rinv[mi][r] = 1.0f / rs[wave * 32 + mi * 16 + g * 4 + r];

  // normalize -> f16 -> direct stores (no LDS stage; L2 merges 32B segments)
  const size_t ybase = (size_t)b * 2048 + q0 + wave * 32;
  for (int mi = 0; mi < 2; ++mi)
    for (int db = 0; db < 4; ++db)
      for (int r = 0; r < 4; ++r)
        Y[(ybase + mi * 16 + g * 4 + r) * 1024 + h * 64 + db * 16 + l16] =
            (f16)(o[mi][db][r] * rinv[mi][r]);
}

// --------------------------- GEMM2: y @ W_proj ------------------------------

__global__ __launch_bounds__(256) void k_gemm_proj(
    const f16* __restrict__ A, const f16* __restrict__ Bt,
    const float* __restrict__ bias, float* __restrict__ out) {
  constexpr int KD = 1024;
  __shared__ __align__(16) f16 As[128 * 64];
  __shared__ __align__(16) f16 Bs[128 * 64];
  const int tid = threadIdx.x;
  const int wave = tid >> 6, lane = tid & 63;
  const int g = lane >> 4, l16 = lane & 15;
  const int m0 = blockIdx.y * 128, n0 = blockIdx.x * 128;
  const int wm = (wave >> 1) * 64, wn = (wave & 1) * 64;
  const int srow = wave * 8 + (lane >> 3);
  const int skc = ((lane & 7) ^ (lane >> 3)) * 8;   // pre-swizzled src chunk

  f32x4 acc[4][4] = {};

  for (int k0 = 0; k0 < KD; k0 += 64) {
    __syncthreads();
    for (int it = 0; it < 4; ++it) {
      gload_lds16(A + (size_t)(m0 + it * 32 + srow) * KD + k0 + skc,
                  As + (it * 32 + wave * 8) * 64);
      gload_lds16(Bt + (size_t)(n0 + it * 32 + srow) * KD + k0 + skc,
                  Bs + (it * 32 + wave * 8) * 64);
    }
    __syncthreads();
    for (int kk = 0; kk < 64; kk += 32) {
      const int ks = kk >> 3;
      f16x8 af[4], bf[4];
      for (int mi = 0; mi < 4; ++mi) {
        int R = wm + mi * 16 + l16, sw = R & 7;
        af[mi] = *(const f16x8*)(As + R * 64 + ((ks + g) ^ sw) * 8);
      }
      for (int ni = 0; ni < 4; ++ni) {
        int R = wn + ni * 16 + l16, sw = R & 7;
        bf[ni] = *(const f16x8*)(Bs + R * 64 + ((ks + g) ^ sw) * 8);
      }
      for (int mi = 0; mi < 4; ++mi)
        for (int ni = 0; ni < 4; ++ni)
          acc[mi][ni] = MFMA16x32(af[mi], bf[ni], acc[mi][ni]);
    }
  }

  float bv[4];
  for (int ni = 0; ni < 4; ++ni) bv[ni] = bias[n0 + wn + ni * 16 + l16];

  for (int mi = 0; mi < 4; ++mi)
    for (int ni = 0; ni < 4; ++ni)
      for (int r = 0; r < 4; ++r) {
        int m = m0 + wm + mi * 16 + g * 4 + r;
        int n = n0 + wn + ni * 16 + l16;
        out[(size_t)m * 1024 + n] = acc[mi][ni][r] + bv[ni];
      }
}

// --------------------------- launch ----------------------------------------

extern "C" void kernel_launch(void* const* d_in, const int* in_sizes, int n_in,
                              void* d_out, int out_size, void* d_ws,
                              size_t ws_size, hipStream_t stream) {
  const float* x      = (const float*)d_in[0];
  const float* W_qkv  = (const float*)d_in[1];
  const float* b_qkv  = (const float*)d_in[2];
  const float* W_proj = (const float*)d_in[3];
  const float* b_proj = (const float*)d_in[4];
  float* out = (float*)d_out;

  char* ws = (char*)d_ws;
  f16* xh    = (f16*)ws;   ws += (size_t)8192 * 1024 * 2;   // also reused as Y
  f16* Wqt   = (f16*)ws;   ws += (size_t)3072 * 1024 * 2;
  f16* Wpt   = (f16*)ws;   ws += (size_t)1024 * 1024 * 2;
  f16* Qb    = (f16*)ws;   ws += (size_t)64 * 2048 * 64 * 2;
  f16* Kb    = (f16*)ws;   ws += (size_t)64 * 2048 * 64 * 2;
  f16* Vt    = (f16*)ws;   ws += (size_t)64 * 64 * 2048 * 2;
  f16* Y = xh;  // xh fully consumed by k_gemm_qkv before k_attn writes Y

  k_prep<<<12288, 256, 0, stream>>>(x, xh, W_qkv, Wqt, W_proj, Wpt);
  k_gemm_qkv<<<dim3(24, 64), 256, 0, stream>>>(xh, Wqt, b_qkv, Qb, Kb, Vt);
  k_attn<<<dim3(64, 16), 256, 0, stream>>>(Qb, Kb, Vt, Y);
  k_gemm_proj<<<dim3(8, 64), 256, 0, stream>>>(Y, Wpt, b_proj, out);
}

// Round 11
// 252.162 us; speedup vs baseline: 1.0464x; 1.0187x over previous
//
#include <hip/hip_runtime.h>

// ---------------------------------------------------------------------------
// CausalSelfAttention: y = proj(attn(qkv(x)))  B=4 T=2048 E=1024 H=16 D=64
// Mask: rows<512 attend cols<512 (full); rows>=512 causal.
// R17: counted-vmcnt pipelined qkv (T3+T4+T5, m201 regime). R16 board: qkv
//     79.4us at the 1-phase serial schedule's ~650 TF class; only the
//     counted-vmcnt schedule breaks it (m196/m218/m248: +28-41%). New qkv:
//     128x256 tile, BK=64, 8 waves (64x64/wave, same frag math as R13),
//     3 LDS slots (144KB, 1 block/CU), prefetch 2 K-tiles ahead, raw
//     s_barrier + s_waitcnt vmcnt(6) (never 0 in-loop; count proof: iter u
//     issues tile u+2's 6 loads -> vmcnt(6) leaves only those in flight =>
//     tile u+1 landed). ds_reads plain C++ (compiler lgkmcnt; rule-18 safe).
//     setprio around MFMA clusters. Epilogue = R13's per-wave 64x64 Es
//     (8x4096 halfs = 64KB <= 144KB, R14 overflow class re-checked).
//     attn reverted to exact R13 (R16's cQT table was neutral-negative).
//     proj/prep unchanged.
// ---------------------------------------------------------------------------

typedef _Float16 f16;
typedef _Float16 f16x4 __attribute__((ext_vector_type(4)));
typedef _Float16 f16x8 __attribute__((ext_vector_type(8)));
typedef float f32x4 __attribute__((ext_vector_type(4)));

#define MFMA16x32(a, b, c) __builtin_amdgcn_mfma_f32_16x16x32_f16(a, b, c, 0, 0, 0)
#define MFMA16x16(a, b, c) __builtin_amdgcn_mfma_f32_16x16x16f16(a, b, c, 0, 0, 0)

__device__ __forceinline__ void gload_lds16(const void* g, void* l) {
  __builtin_amdgcn_global_load_lds(
      (__attribute__((address_space(1))) void*)g,
      (__attribute__((address_space(3))) void*)l, 16, 0, 0);
}

// --------------------------- prep: cast + transposes (one launch) ----------

__global__ __launch_bounds__(256) void k_prep(
    const float* __restrict__ x, f16* __restrict__ xh,
    const float* __restrict__ Wq, f16* __restrict__ Wqt,
    const float* __restrict__ Wp, f16* __restrict__ Wpt) {
  __shared__ float tile[32][33];
  const int bid = blockIdx.x;
  if (bid < 8192) {
    int i = bid * 256 + threadIdx.x;
    float4 v = ((const float4*)x)[i];
    f16x4 o = {(f16)v.x, (f16)v.y, (f16)v.z, (f16)v.w};
    ((f16x4*)xh)[i] = o;
    return;
  }
  const float* W;
  f16* Wt;
  int Ndim, bx, by;
  if (bid < 8192 + 3072) {
    int r = bid - 8192;
    W = Wq; Wt = Wqt; Ndim = 3072; bx = r % 96; by = r / 96;
  } else {
    int r = bid - 11264;
    W = Wp; Wt = Wpt; Ndim = 1024; bx = r % 32; by = r / 32;
  }
  const int tx = threadIdx.x & 31, ty = threadIdx.x >> 5;
  const int n = bx * 32 + tx;
  const int k0 = by * 32;
  for (int j = ty; j < 32; j += 8)
    tile[j][tx] = W[(size_t)(k0 + j) * Ndim + n];
  __syncthreads();
  const int k = k0 + tx;
  for (int j = ty; j < 32; j += 8)
    Wt[(size_t)(bx * 32 + j) * 1024 + k] = (f16)tile[tx][j];
}

// --------------------------- GEMM1: x @ W_qkv (pipelined) -------------------
// A [8192][1024] f16, Bt [3072][1024] f16 (W^T). 128x256 tile, BK=64,
// 8 waves (2M x 4N, 64x64 per wave). 3 staging slots (A 128x64 + B 256x64
// = 48KB each, 144KB total, 1 block/CU). Iter u: issue tile u+2 (6 loads:
// 3 in kk0-phase, 3 in kk1-phase) into slot (u+2)%3 (freed by prev barrier);
// compute tile u from slot u%3 in 2 MFMA clusters; end: vmcnt(6) (tile u+1
// landed; never 0 until drain) + raw s_barrier. Source-side XOR pre-swizzle,
// linear LDS dest, swizzled fragment reads (R13 involution). Epilogue:
// per-wave 64x64 Es stage (smem reuse) -> b128 stores to Q/K/Vt.

__global__ __launch_bounds__(512, 2) void k_gemm_qkv(
    const f16* __restrict__ A, const f16* __restrict__ Bt,
    const float* __restrict__ bias,
    f16* __restrict__ Qo, f16* __restrict__ Ko, f16* __restrict__ Vo) {
  constexpr int KD = 1024;
  constexpr int SLOT = (128 + 256) * 64;            // 24576 halfs / slot
  __shared__ __align__(16) f16 smem[3 * SLOT];      // 144KB
  const int tid = threadIdx.x;
  const int wave = tid >> 6, lane = tid & 63;
  const int g = lane >> 4, l16 = lane & 15;
  const int m0 = blockIdx.y * 128, n0 = blockIdx.x * 256;
  const int wm = (wave >> 2) * 64, wn = (wave & 3) * 64;
  const int srow = wave * 8 + (lane >> 3);          // staging row in 64-group
  const int skc = ((lane & 7) ^ (lane >> 3)) * 8;   // pre-swizzled src chunk

  f32x4 acc[4][4] = {};

  // prologue: stage tiles 0 and 1 into slots 0,1 (6 issues each)
  for (int t = 0; t < 2; ++t) {
    f16* Sa = smem + t * SLOT;
    f16* Sb = Sa + 128 * 64;
    for (int it = 0; it < 2; ++it)
      gload_lds16(A + (size_t)(m0 + it * 64 + srow) * KD + t * 64 + skc,
                  Sa + (it * 64 + wave * 8) * 64);
    for (int it = 0; it < 4; ++it)
      gload_lds16(Bt + (size_t)(n0 + it * 64 + srow) * KD + t * 64 + skc,
                  Sb + (it * 64 + wave * 8) * 64);
  }
  // tile 0 landed when <=6 (tile 1's) remain in flight
  asm volatile("s_waitcnt vmcnt(6)" ::: "memory");
  __builtin_amdgcn_s_barrier();

  for (int u = 0; u < 16; ++u) {
    const int s = u % 3;
    f16* Sa = smem + s * SLOT;
    f16* Sb = Sa + 128 * 64;
    const bool pf = (u + 2) < 16;
    f16* Pa = smem + ((u + 2) % 3) * SLOT;
    f16* Pb = Pa + 128 * 64;
    const int kp = (u + 2) * 64;

    for (int kk = 0; kk < 2; ++kk) {
      // prefetch half: 3 of tile u+2's 6 issues (slot freed by prev barrier)
      if (pf) {
        if (kk == 0) {
          gload_lds16(A + (size_t)(m0 + srow) * KD + kp + skc,
                      Pa + (wave * 8) * 64);
          gload_lds16(A + (size_t)(m0 + 64 + srow) * KD + kp + skc,
                      Pa + (64 + wave * 8) * 64);
          gload_lds16(Bt + (size_t)(n0 + srow) * KD + kp + skc,
                      Pb + (wave * 8) * 64);
        } else {
          gload_lds16(Bt + (size_t)(n0 + 64 + srow) * KD + kp + skc,
                      Pb + (64 + wave * 8) * 64);
          gload_lds16(Bt + (size_t)(n0 + 128 + srow) * KD + kp + skc,
                      Pb + (128 + wave * 8) * 64);
          gload_lds16(Bt + (size_t)(n0 + 192 + srow) * KD + kp + skc,
                      Pb + (192 + wave * 8) * 64);
        }
      }

      const int ks = kk * 4;  // chunk slot base: 0 or 4
      f16x8 af[4], bf[4];
      for (int mi = 0; mi < 4; ++mi) {
        int R = wm + mi * 16 + l16, sw = R & 7;
        af[mi] = *(const f16x8*)(Sa + R * 64 + ((ks + g) ^ sw) * 8);
      }
      for (int ni = 0; ni < 4; ++ni) {
        int R = wn + ni * 16 + l16, sw = R & 7;
        bf[ni] = *(const f16x8*)(Sb + R * 64 + ((ks + g) ^ sw) * 8);
      }
      __builtin_amdgcn_s_setprio(1);
      for (int mi = 0; mi < 4; ++mi)
        for (int ni = 0; ni < 4; ++ni)
          acc[mi][ni] = MFMA16x32(af[mi], bf[ni], acc[mi][ni]);
      __builtin_amdgcn_s_setprio(0);
    }

    // end of iter: tile u+1 landed (only tile u+2's 6 may remain in flight);
    // barrier frees slot (u+3)%3 for the next iter's issues.
    if (u < 14)
      asm volatile("s_waitcnt vmcnt(6)" ::: "memory");
    else
      asm volatile("s_waitcnt vmcnt(0)" ::: "memory");
    __builtin_amdgcn_s_barrier();
  }

  // ---- epilogue: per-wave 64x64 swizzled stage (smem reuse; 8x4096=64KB) --
  const int nsub = n0 + wn;            // multiple of 64 -> one (part, head)
  const int part = nsub >> 10;         // 0=Q 1=K 2=V
  const int h    = (nsub >> 6) & 15;
  const int mg   = m0 + wm;
  const int b    = mg >> 11;
  const int tb   = mg & 2047;
  const size_t bh = (size_t)(b * 16 + h);

  float bv[4];
  for (int ni = 0; ni < 4; ++ni) bv[ni] = bias[nsub + ni * 16 + l16];

  f16* Es = smem + wave * 4096;  // 64x64, chunk-XOR swizzled by row&7

  for (int mi = 0; mi < 4; ++mi)
    for (int ni = 0; ni < 4; ++ni)
      for (int r = 0; r < 4; ++r) {
        f16 hv = (f16)(acc[mi][ni][r] + bv[ni]);
        int mrow = mi * 16 + g * 4 + r, ncol = ni * 16 + l16;
        if (part == 2)  // store transposed: [d][t]
          Es[ncol * 64 + (mrow ^ ((ncol & 7) << 3))] = hv;
        else            // [t][d]
          Es[mrow * 64 + (ncol ^ ((mrow & 7) << 3))] = hv;
      }
  // same-wave DS write->read: LDS pipe in-order, no barrier needed

  const int rrow = lane >> 3, rj = lane & 7;
  for (int p = 0; p < 8; ++p) {
    int row = p * 8 + rrow;
    f16x8 vv = *(const f16x8*)(Es + row * 64 + (rj ^ (row & 7)) * 8);
    int rcol = rj * 8;
    if (part == 0)
      *(f16x8*)(Qo + (bh * 2048 + tb + row) * 64 + rcol) = vv;
    else if (part == 1)
      *(f16x8*)(Ko + (bh * 2048 + tb + row) * 64 + rcol) = vv;
    else  // row is d, rcol is t-offset
      *(f16x8*)(Vo + (bh * 64 + row) * 2048 + tb + rcol) = vv;
  }
}

// --------------------------- flash attention (1 q-tile / block) -------------
// grid (64 bh, 16 qt-slots); block 256 = 4 waves; wave owns 32 q-rows.
// qt = 15 - blockIdx.y (heavy tiles dispatch first). Block owns the full
// K-range of its q-tile (nt = qt<4 ? 8 : 2(qt+1) k-tiles): fixed-max softmax,
// rsum in-wave -> normalize in-register -> direct f16 Y stores. LDS 33KB ->
// 4 blocks/CU. T5 setprio around MFMA clusters.  (Exact R13 kernel.)

__global__ __launch_bounds__(256, 4) void k_attn(
    const f16* __restrict__ Q, const f16* __restrict__ Kb,
    const f16* __restrict__ Vt, f16* __restrict__ Y) {
  __shared__ __align__(16) f16 Ks[2][64 * 64];
  __shared__ __align__(16) f16 Vs[2][64 * 64];
  __shared__ float rs[4 * 32];  // per-wave row sums

  const int tid = threadIdx.x;
  const int wave = tid >> 6, lane = tid & 63;
  const int g = lane >> 4, l16 = lane & 15;
  const int bh = blockIdx.x;
  const int b = bh >> 4, h = bh & 15;
  const int qt = 15 - blockIdx.y;
  const int q0 = qt * 128;
  const int nt = (qt < 4) ? 8 : (qt + 1) * 2;  // k-tiles for this q-tile
  const int srowrel = lane >> 3;
  const int sc = (lane & 7) ^ srowrel;  // XOR-swizzled staging chunk

  const f32x4 sinit = {-8.65617025f, -8.65617025f, -8.65617025f, -8.65617025f};

  // Q B-fragments (operand-swapped QK), pre-scaled by log2(e)/8
  f16x8 aq[2][2];
  for (int mi = 0; mi < 2; ++mi) {
    const f16* qrow =
        Q + ((size_t)bh * 2048 + q0 + wave * 32 + mi * 16 + l16) * 64 + g * 8;
    aq[mi][0] = *(const f16x8*)(qrow);
    aq[mi][1] = *(const f16x8*)(qrow + 32);
    for (int kb = 0; kb < 2; ++kb)
      aq[mi][kb] = aq[mi][kb] * (f16)0.18033688f;
  }

  f32x4 o[2][4] = {};       // o[mi][db]: O[m=g*4+r][d=db*16+l16]
  float rsum[2] = {};       // per-lane partial for row m=l16 (quad's k share)

  // prologue: stage tile 0 into buf 0 (each wave: 16 K rows + 16 V rows)
  for (int it = 0; it < 2; ++it) {
    int row = it * 32 + wave * 8 + srowrel;
    gload_lds16(Kb + ((size_t)bh * 2048 + row) * 64 + sc * 8,
                &Ks[0][(it * 32 + wave * 8) * 64]);
    gload_lds16(Vt + ((size_t)bh * 64 + row) * 2048 + sc * 8,
                &Vs[0][(it * 32 + wave * 8) * 64]);
  }
  __syncthreads();

  int cur = 0;
  for (int i = 0; i < nt; ++i) {
    // ---- stage tile i+1 into buf cur^1 (readers joined at barrier i-1) ----
    if (i + 1 < nt) {
      const int kn0 = (i + 1) << 6;
      for (int it = 0; it < 2; ++it) {
        int row = it * 32 + wave * 8 + srowrel;
        gload_lds16(Kb + ((size_t)bh * 2048 + kn0 + row) * 64 + sc * 8,
                    &Ks[cur ^ 1][(it * 32 + wave * 8) * 64]);
        gload_lds16(Vt + ((size_t)bh * 64 + row) * 2048 + kn0 + sc * 8,
                    &Vs[cur ^ 1][(it * 32 + wave * 8) * 64]);
      }
    }

    // ---- compute tile i from buf cur ----
    const int kt0 = i << 6;
    const f16* Kc = Ks[cur];
    const f16* Vc = Vs[cur];

    // T = K Q^T : T[k=g*4+r][m=l16] per nb (k-block), mi (q-block)
    f32x4 t[2][4];
    __builtin_amdgcn_s_setprio(1);
    for (int nb = 0; nb < 4; ++nb) {
      int R = nb * 16 + l16, sw = R & 7;
      f16x8 bk0 = *(const f16x8*)(Kc + R * 64 + ((0 + g) ^ sw) * 8);
      f16x8 bk1 = *(const f16x8*)(Kc + R * 64 + ((4 + g) ^ sw) * 8);
      for (int mi = 0; mi < 2; ++mi) {
        f32x4 acc = MFMA16x32(bk0, aq[mi][0], sinit);
        t[mi][nb] = MFMA16x32(bk1, aq[mi][1], acc);
      }
    }
    __builtin_amdgcn_s_setprio(0);

    // exp -> P stays in registers as 16x16x16 A-frags ap[nb][mi]
    const bool masked = (q0 >= 512) && (kt0 >= q0);
    f16x4 ap[4][2];
    for (int mi = 0; mi < 2; ++mi) {
      const int mrow = q0 + wave * 32 + mi * 16 + l16;
      for (int nb = 0; nb < 4; ++nb)
        for (int r = 0; r < 4; ++r) {
          float pv = __builtin_amdgcn_exp2f(t[mi][nb][r]);
          if (masked && (kt0 + nb * 16 + g * 4 + r > mrow)) pv = 0.f;
          rsum[mi] += pv;
          ap[nb][mi][r] = (f16)pv;
        }
    }

    // O += P V : A = ap (in-register), B = V^T b64 frags from LDS
    __builtin_amdgcn_s_setprio(1);
    for (int db = 0; db < 4; ++db)
      for (int nb = 0; nb < 4; ++nb) {
        int R = db * 16 + l16, sw = R & 7;
        int c = nb * 2 + (g >> 1);
        f16x4 bv = *(const f16x4*)(Vc + R * 64 + (c ^ sw) * 8 + (g & 1) * 4);
        for (int mi = 0; mi < 2; ++mi)
          o[mi][db] = MFMA16x16(ap[nb][mi], bv, o[mi][db]);
      }
    __builtin_amdgcn_s_setprio(0);

    __syncthreads();  // joins all waves' reads of buf cur + drains stages
    cur ^= 1;
  }

  // reduce rsum across quads: all lanes with same l16 get the row total
  for (int mi = 0; mi < 2; ++mi) {
    rsum[mi] += __shfl_xor(rsum[mi], 16, 64);
    rsum[mi] += __shfl_xor(rsum[mi], 32, 64);
  }

  // broadcast row totals to the lanes that hold O rows g*4+r (via LDS)
  if (g == 0)
    for (int mi = 0; mi < 2; ++mi) rs[wave * 32 + mi * 16 + l16] = rsum[mi];
  // same-wave DS write->read: LDS pipe in-order, no barrier needed
  float rinv[2][4];
  for (int mi = 0; mi < 2; ++mi)
    for (int r = 0; r < 4; ++r)
      rinv[mi][r] = 1.0f / rs[wave * 32 + mi * 16 + g * 4 + r];

  // normalize -> f16 -> direct stores (no LDS stage; L2 merges 32B segments)
  const size_t ybase = (size_t)b * 2048 + q0 + wave * 32;
  for (int mi = 0; mi < 2; ++mi)
    for (int db = 0; db < 4; ++db)
      for (int r = 0; r < 4; ++r)
        Y[(ybase + mi * 16 + g * 4 + r) * 1024 + h * 64 + db * 16 + l16] =
            (f16)(o[mi][db][r] * rinv[mi][r]);
}

// --------------------------- GEMM2: y @ W_proj ------------------------------

__global__ __launch_bounds__(256) void k_gemm_proj(
    const f16* __restrict__ A, const f16* __restrict__ Bt,
    const float* __restrict__ bias, float* __restrict__ out) {
  constexpr int KD = 1024;
  __shared__ __align__(16) f16 As[128 * 64];
  __shared__ __align__(16) f16 Bs[128 * 64];
  const int tid = threadIdx.x;
  const int wave = tid >> 6, lane = tid & 63;
  const int g = lane >> 4, l16 = lane & 15;
  const int m0 = blockIdx.y * 128, n0 = blockIdx.x * 128;
  const int wm = (wave >> 1) * 64, wn = (wave & 1) * 64;
  const int srow = wave * 8 + (lane >> 3);
  const int skc = ((lane & 7) ^ (lane >> 3)) * 8;   // pre-swizzled src chunk

  f32x4 acc[4][4] = {};

  for (int k0 = 0; k0 < KD; k0 += 64) {
    __syncthreads();
    for (int it = 0; it < 4; ++it) {
      gload_lds16(A + (size_t)(m0 + it * 32 + srow) * KD + k0 + skc,
                  As + (it * 32 + wave * 8) * 64);
      gload_lds16(Bt + (size_t)(n0 + it * 32 + srow) * KD + k0 + skc,
                  Bs + (it * 32 + wave * 8) * 64);
    }
    __syncthreads();
    for (int kk = 0; kk < 64; kk += 32) {
      const int ks = kk >> 3;
      f16x8 af[4], bf[4];
      for (int mi = 0; mi < 4; ++mi) {
        int R = wm + mi * 16 + l16, sw = R & 7;
        af[mi] = *(const f16x8*)(As + R * 64 + ((ks + g) ^ sw) * 8);
      }
      for (int ni = 0; ni < 4; ++ni) {
        int R = wn + ni * 16 + l16, sw = R & 7;
        bf[ni] = *(const f16x8*)(Bs + R * 64 + ((ks + g) ^ sw) * 8);
      }
      for (int mi = 0; mi < 4; ++mi)
        for (int ni = 0; ni < 4; ++ni)
          acc[mi][ni] = MFMA16x32(af[mi], bf[ni], acc[mi][ni]);
    }
  }

  float bv[4];
  for (int ni = 0; ni < 4; ++ni) bv[ni] = bias[n0 + wn + ni * 16 + l16];

  for (int mi = 0; mi < 4; ++mi)
    for (int ni = 0; ni < 4; ++ni)
      for (int r = 0; r < 4; ++r) {
        int m = m0 + wm + mi * 16 + g * 4 + r;
        int n = n0 + wn + ni * 16 + l16;
        out[(size_t)m * 1024 + n] = acc[mi][ni][r] + bv[ni];
      }
}

// --------------------------- launch ----------------------------------------

extern "C" void kernel_launch(void* const* d_in, const int* in_sizes, int n_in,
                              void* d_out, int out_size, void* d_ws,
                              size_t ws_size, hipStream_t stream) {
  const float* x      = (const float*)d_in[0];
  const float* W_qkv  = (const float*)d_in[1];
  const float* b_qkv  = (const float*)d_in[2];
  const float* W_proj = (const float*)d_in[3];
  const float* b_proj = (const float*)d_in[4];
  float* out = (float*)d_out;

  char* ws = (char*)d_ws;
  f16* xh    = (f16*)ws;   ws += (size_t)8192 * 1024 * 2;   // also reused as Y
  f16* Wqt   = (f16*)ws;   ws += (size_t)3072 * 1024 * 2;
  f16* Wpt   = (f16*)ws;   ws += (size_t)1024 * 1024 * 2;
  f16* Qb    = (f16*)ws;   ws += (size_t)64 * 2048 * 64 * 2;
  f16* Kb    = (f16*)ws;   ws += (size_t)64 * 2048 * 64 * 2;
  f16* Vt    = (f16*)ws;   ws += (size_t)64 * 64 * 2048 * 2;
  f16* Y = xh;  // xh fully consumed by k_gemm_qkv before k_attn writes Y

  k_prep<<<12288, 256, 0, stream>>>(x, xh, W_qkv, Wqt, W_proj, Wpt);
  k_gemm_qkv<<<dim3(12, 64), 512, 0, stream>>>(xh, Wqt, b_qkv, Qb, Kb, Vt);
  k_attn<<<dim3(64, 16), 256, 0, stream>>>(Qb, Kb, Vt, Y);
  k_gemm_proj<<<dim3(8, 64), 256, 0, stream>>>(Y, Wpt, b_proj, out);
}

// Round 12
// 246.965 us; speedup vs baseline: 1.0684x; 1.0210x over previous
//
#include <hip/hip_runtime.h>

// ---------------------------------------------------------------------------
// CausalSelfAttention: y = proj(attn(qkv(x)))  B=4 T=2048 E=1024 H=16 D=64
// Mask: rows<512 attend cols<512 (full); rows>=512 causal.
// R18: (a) proj -> R17's counted-vmcnt pipeline verbatim (qkv went 79->65us,
//     MfmaUtil 26->32; proj is the same 1-phase class). 128x256, 3 slots,
//     vmcnt(6) never 0 in-loop, setprio clusters; epilogue = f32 stores.
//     grid 4x64 = 256 blocks = 1/CU.
//     (b) attn rsum via ones-B MFMA: ap[nb][mi] holds P[m=l16][k=g*4+r];
//     MFMA16x16x16(ap, ones) yields D[row=g*4+r] = rowsum(P) at exactly the
//     (lane,reg) the o-normalization needs -> 8 tiny MFMAs replace 32 VALU
//     adds AND delete the shfl_xor reduce + rs LDS broadcast. rsum now sums
//     the same f16 P that PV consumes (consistent; same error class).
//     qkv (R17 pipelined) and prep unchanged.
// ---------------------------------------------------------------------------

typedef _Float16 f16;
typedef _Float16 f16x4 __attribute__((ext_vector_type(4)));
typedef _Float16 f16x8 __attribute__((ext_vector_type(8)));
typedef float f32x4 __attribute__((ext_vector_type(4)));

#define MFMA16x32(a, b, c) __builtin_amdgcn_mfma_f32_16x16x32_f16(a, b, c, 0, 0, 0)
#define MFMA16x16(a, b, c) __builtin_amdgcn_mfma_f32_16x16x16f16(a, b, c, 0, 0, 0)

__device__ __forceinline__ void gload_lds16(const void* g, void* l) {
  __builtin_amdgcn_global_load_lds(
      (__attribute__((address_space(1))) void*)g,
      (__attribute__((address_space(3))) void*)l, 16, 0, 0);
}

// --------------------------- prep: cast + transposes (one launch) ----------

__global__ __launch_bounds__(256) void k_prep(
    const float* __restrict__ x, f16* __restrict__ xh,
    const float* __restrict__ Wq, f16* __restrict__ Wqt,
    const float* __restrict__ Wp, f16* __restrict__ Wpt) {
  __shared__ float tile[32][33];
  const int bid = blockIdx.x;
  if (bid < 8192) {
    int i = bid * 256 + threadIdx.x;
    float4 v = ((const float4*)x)[i];
    f16x4 o = {(f16)v.x, (f16)v.y, (f16)v.z, (f16)v.w};
    ((f16x4*)xh)[i] = o;
    return;
  }
  const float* W;
  f16* Wt;
  int Ndim, bx, by;
  if (bid < 8192 + 3072) {
    int r = bid - 8192;
    W = Wq; Wt = Wqt; Ndim = 3072; bx = r % 96; by = r / 96;
  } else {
    int r = bid - 11264;
    W = Wp; Wt = Wpt; Ndim = 1024; bx = r % 32; by = r / 32;
  }
  const int tx = threadIdx.x & 31, ty = threadIdx.x >> 5;
  const int n = bx * 32 + tx;
  const int k0 = by * 32;
  for (int j = ty; j < 32; j += 8)
    tile[j][tx] = W[(size_t)(k0 + j) * Ndim + n];
  __syncthreads();
  const int k = k0 + tx;
  for (int j = ty; j < 32; j += 8)
    Wt[(size_t)(bx * 32 + j) * 1024 + k] = (f16)tile[tx][j];
}

// --------------------------- GEMM1: x @ W_qkv (pipelined, R17) --------------
// 128x256 tile, BK=64, 8 waves (64x64/wave), 3 LDS slots (144KB, 1 block/CU),
// prefetch 2 K-tiles ahead, vmcnt(6) never 0 in-loop. Source-side XOR
// pre-swizzle, linear LDS dest, swizzled fragment reads. Epilogue: per-wave
// 64x64 Es stage (smem reuse, 8x4096=64KB) -> b128 stores to Q/K/Vt.

__global__ __launch_bounds__(512, 2) void k_gemm_qkv(
    const f16* __restrict__ A, const f16* __restrict__ Bt,
    const float* __restrict__ bias,
    f16* __restrict__ Qo, f16* __restrict__ Ko, f16* __restrict__ Vo) {
  constexpr int KD = 1024;
  constexpr int SLOT = (128 + 256) * 64;            // 24576 halfs / slot
  __shared__ __align__(16) f16 smem[3 * SLOT];      // 144KB
  const int tid = threadIdx.x;
  const int wave = tid >> 6, lane = tid & 63;
  const int g = lane >> 4, l16 = lane & 15;
  const int m0 = blockIdx.y * 128, n0 = blockIdx.x * 256;
  const int wm = (wave >> 2) * 64, wn = (wave & 3) * 64;
  const int srow = wave * 8 + (lane >> 3);          // staging row in 64-group
  const int skc = ((lane & 7) ^ (lane >> 3)) * 8;   // pre-swizzled src chunk

  f32x4 acc[4][4] = {};

  // prologue: stage tiles 0 and 1 into slots 0,1 (6 issues each)
  for (int t = 0; t < 2; ++t) {
    f16* Sa = smem + t * SLOT;
    f16* Sb = Sa + 128 * 64;
    for (int it = 0; it < 2; ++it)
      gload_lds16(A + (size_t)(m0 + it * 64 + srow) * KD + t * 64 + skc,
                  Sa + (it * 64 + wave * 8) * 64);
    for (int it = 0; it < 4; ++it)
      gload_lds16(Bt + (size_t)(n0 + it * 64 + srow) * KD + t * 64 + skc,
                  Sb + (it * 64 + wave * 8) * 64);
  }
  asm volatile("s_waitcnt vmcnt(6)" ::: "memory");
  __builtin_amdgcn_s_barrier();

  for (int u = 0; u < 16; ++u) {
    const int s = u % 3;
    f16* Sa = smem + s * SLOT;
    f16* Sb = Sa + 128 * 64;
    const bool pf = (u + 2) < 16;
    f16* Pa = smem + ((u + 2) % 3) * SLOT;
    f16* Pb = Pa + 128 * 64;
    const int kp = (u + 2) * 64;

    for (int kk = 0; kk < 2; ++kk) {
      if (pf) {
        if (kk == 0) {
          gload_lds16(A + (size_t)(m0 + srow) * KD + kp + skc,
                      Pa + (wave * 8) * 64);
          gload_lds16(A + (size_t)(m0 + 64 + srow) * KD + kp + skc,
                      Pa + (64 + wave * 8) * 64);
          gload_lds16(Bt + (size_t)(n0 + srow) * KD + kp + skc,
                      Pb + (wave * 8) * 64);
        } else {
          gload_lds16(Bt + (size_t)(n0 + 64 + srow) * KD + kp + skc,
                      Pb + (64 + wave * 8) * 64);
          gload_lds16(Bt + (size_t)(n0 + 128 + srow) * KD + kp + skc,
                      Pb + (128 + wave * 8) * 64);
          gload_lds16(Bt + (size_t)(n0 + 192 + srow) * KD + kp + skc,
                      Pb + (192 + wave * 8) * 64);
        }
      }

      const int ks = kk * 4;  // chunk slot base: 0 or 4
      f16x8 af[4], bf[4];
      for (int mi = 0; mi < 4; ++mi) {
        int R = wm + mi * 16 + l16, sw = R & 7;
        af[mi] = *(const f16x8*)(Sa + R * 64 + ((ks + g) ^ sw) * 8);
      }
      for (int ni = 0; ni < 4; ++ni) {
        int R = wn + ni * 16 + l16, sw = R & 7;
        bf[ni] = *(const f16x8*)(Sb + R * 64 + ((ks + g) ^ sw) * 8);
      }
      __builtin_amdgcn_s_setprio(1);
      for (int mi = 0; mi < 4; ++mi)
        for (int ni = 0; ni < 4; ++ni)
          acc[mi][ni] = MFMA16x32(af[mi], bf[ni], acc[mi][ni]);
      __builtin_amdgcn_s_setprio(0);
    }

    if (u < 14)
      asm volatile("s_waitcnt vmcnt(6)" ::: "memory");
    else
      asm volatile("s_waitcnt vmcnt(0)" ::: "memory");
    __builtin_amdgcn_s_barrier();
  }

  // ---- epilogue: per-wave 64x64 swizzled stage (smem reuse) ----
  const int nsub = n0 + wn;            // multiple of 64 -> one (part, head)
  const int part = nsub >> 10;         // 0=Q 1=K 2=V
  const int h    = (nsub >> 6) & 15;
  const int mg   = m0 + wm;
  const int b    = mg >> 11;
  const int tb   = mg & 2047;
  const size_t bh = (size_t)(b * 16 + h);

  float bv[4];
  for (int ni = 0; ni < 4; ++ni) bv[ni] = bias[nsub + ni * 16 + l16];

  f16* Es = smem + wave * 4096;  // 64x64, chunk-XOR swizzled by row&7

  for (int mi = 0; mi < 4; ++mi)
    for (int ni = 0; ni < 4; ++ni)
      for (int r = 0; r < 4; ++r) {
        f16 hv = (f16)(acc[mi][ni][r] + bv[ni]);
        int mrow = mi * 16 + g * 4 + r, ncol = ni * 16 + l16;
        if (part == 2)  // store transposed: [d][t]
          Es[ncol * 64 + (mrow ^ ((ncol & 7) << 3))] = hv;
        else            // [t][d]
          Es[mrow * 64 + (ncol ^ ((mrow & 7) << 3))] = hv;
      }
  // same-wave DS write->read: LDS pipe in-order, no barrier needed

  const int rrow = lane >> 3, rj = lane & 7;
  for (int p = 0; p < 8; ++p) {
    int row = p * 8 + rrow;
    f16x8 vv = *(const f16x8*)(Es + row * 64 + (rj ^ (row & 7)) * 8);
    int rcol = rj * 8;
    if (part == 0)
      *(f16x8*)(Qo + (bh * 2048 + tb + row) * 64 + rcol) = vv;
    else if (part == 1)
      *(f16x8*)(Ko + (bh * 2048 + tb + row) * 64 + rcol) = vv;
    else  // row is d, rcol is t-offset
      *(f16x8*)(Vo + (bh * 64 + row) * 2048 + tb + rcol) = vv;
  }
}

// --------------------------- flash attention (1 q-tile / block) -------------
// grid (64 bh, 16 qt-slots); block 256 = 4 waves; wave owns 32 q-rows.
// qt = 15 - blockIdx.y. Block owns the full K-range of its q-tile: fixed-max
// softmax; rowsum accumulated by ones-B MFMA into rs_acc[mi][r] at the same
// (lane,reg) position o[mi][db][r] needs -> no shfl/LDS reduce. Direct f16 Y
// stores. LDS 32.8KB -> 4 blocks/CU. T5 setprio around MFMA clusters.

__global__ __launch_bounds__(256, 4) void k_attn(
    const f16* __restrict__ Q, const f16* __restrict__ Kb,
    const f16* __restrict__ Vt, f16* __restrict__ Y) {
  __shared__ __align__(16) f16 Ks[2][64 * 64];
  __shared__ __align__(16) f16 Vs[2][64 * 64];

  const int tid = threadIdx.x;
  const int wave = tid >> 6, lane = tid & 63;
  const int g = lane >> 4, l16 = lane & 15;
  const int bh = blockIdx.x;
  const int b = bh >> 4, h = bh & 15;
  const int qt = 15 - blockIdx.y;
  const int q0 = qt * 128;
  const int nt = (qt < 4) ? 8 : (qt + 1) * 2;  // k-tiles for this q-tile
  const int srowrel = lane >> 3;
  const int sc = (lane & 7) ^ srowrel;  // XOR-swizzled staging chunk

  const f32x4 sinit = {-8.65617025f, -8.65617025f, -8.65617025f, -8.65617025f};
  const f16x4 vone = {(f16)1.f, (f16)1.f, (f16)1.f, (f16)1.f};

  // Q B-fragments (operand-swapped QK), pre-scaled by log2(e)/8
  f16x8 aq[2][2];
  for (int mi = 0; mi < 2; ++mi) {
    const f16* qrow =
        Q + ((size_t)bh * 2048 + q0 + wave * 32 + mi * 16 + l16) * 64 + g * 8;
    aq[mi][0] = *(const f16x8*)(qrow);
    aq[mi][1] = *(const f16x8*)(qrow + 32);
    for (int kb = 0; kb < 2; ++kb)
      aq[mi][kb] = aq[mi][kb] * (f16)0.18033688f;
  }

  f32x4 o[2][4] = {};     // o[mi][db]: O[m=g*4+r][d=db*16+l16]
  f32x4 rs_acc[2] = {};   // rs_acc[mi][r] = rowsum P for row g*4+r (all l16)

  // prologue: stage tile 0 into buf 0 (each wave: 16 K rows + 16 V rows)
  for (int it = 0; it < 2; ++it) {
    int row = it * 32 + wave * 8 + srowrel;
    gload_lds16(Kb + ((size_t)bh * 2048 + row) * 64 + sc * 8,
                &Ks[0][(it * 32 + wave * 8) * 64]);
    gload_lds16(Vt + ((size_t)bh * 64 + row) * 2048 + sc * 8,
                &Vs[0][(it * 32 + wave * 8) * 64]);
  }
  __syncthreads();

  int cur = 0;
  for (int i = 0; i < nt; ++i) {
    // ---- stage tile i+1 into buf cur^1 (readers joined at barrier i-1) ----
    if (i + 1 < nt) {
      const int kn0 = (i + 1) << 6;
      for (int it = 0; it < 2; ++it) {
        int row = it * 32 + wave * 8 + srowrel;
        gload_lds16(Kb + ((size_t)bh * 2048 + kn0 + row) * 64 + sc * 8,
                    &Ks[cur ^ 1][(it * 32 + wave * 8) * 64]);
        gload_lds16(Vt + ((size_t)bh * 64 + row) * 2048 + kn0 + sc * 8,
                    &Vs[cur ^ 1][(it * 32 + wave * 8) * 64]);
      }
    }

    // ---- compute tile i from buf cur ----
    const int kt0 = i << 6;
    const f16* Kc = Ks[cur];
    const f16* Vc = Vs[cur];

    // T = K Q^T : T[k=g*4+r][m=l16] per nb (k-block), mi (q-block)
    f32x4 t[2][4];
    __builtin_amdgcn_s_setprio(1);
    for (int nb = 0; nb < 4; ++nb) {
      int R = nb * 16 + l16, sw = R & 7;
      f16x8 bk0 = *(const f16x8*)(Kc + R * 64 + ((0 + g) ^ sw) * 8);
      f16x8 bk1 = *(const f16x8*)(Kc + R * 64 + ((4 + g) ^ sw) * 8);
      for (int mi = 0; mi < 2; ++mi) {
        f32x4 acc = MFMA16x32(bk0, aq[mi][0], sinit);
        t[mi][nb] = MFMA16x32(bk1, aq[mi][1], acc);
      }
    }
    __builtin_amdgcn_s_setprio(0);

    // exp -> P stays in registers as 16x16x16 A-frags ap[nb][mi]
    const bool masked = (q0 >= 512) && (kt0 >= q0);
    f16x4 ap[4][2];
    for (int mi = 0; mi < 2; ++mi) {
      const int mrow = q0 + wave * 32 + mi * 16 + l16;
      for (int nb = 0; nb < 4; ++nb)
        for (int r = 0; r < 4; ++r) {
          float pv = __builtin_amdgcn_exp2f(t[mi][nb][r]);
          if (masked && (kt0 + nb * 16 + g * 4 + r > mrow)) pv = 0.f;
          ap[nb][mi][r] = (f16)pv;
        }
    }

    // O += P V (+ rowsum via ones-B): A = ap, B = V^T b64 frags from LDS
    __builtin_amdgcn_s_setprio(1);
    for (int nb = 0; nb < 4; ++nb)
      for (int mi = 0; mi < 2; ++mi)
        rs_acc[mi] = MFMA16x16(ap[nb][mi], vone, rs_acc[mi]);
    for (int db = 0; db < 4; ++db)
      for (int nb = 0; nb < 4; ++nb) {
        int R = db * 16 + l16, sw = R & 7;
        int c = nb * 2 + (g >> 1);
        f16x4 bv = *(const f16x4*)(Vc + R * 64 + (c ^ sw) * 8 + (g & 1) * 4);
        for (int mi = 0; mi < 2; ++mi)
          o[mi][db] = MFMA16x16(ap[nb][mi], bv, o[mi][db]);
      }
    __builtin_amdgcn_s_setprio(0);

    __syncthreads();  // joins all waves' reads of buf cur + drains stages
    cur ^= 1;
  }

  // normalize -> f16 -> direct stores; rs_acc[mi][r] is already the row total
  // for row g*4+r (every l16 column of the ones-B MFMA output is the rowsum).
  float rinv[2][4];
  for (int mi = 0; mi < 2; ++mi)
    for (int r = 0; r < 4; ++r)
      rinv[mi][r] = 1.0f / rs_acc[mi][r];

  const size_t ybase = (size_t)b * 2048 + q0 + wave * 32;
  for (int mi = 0; mi < 2; ++mi)
    for (int db = 0; db < 4; ++db)
      for (int r = 0; r < 4; ++r)
        Y[(ybase + mi * 16 + g * 4 + r) * 1024 + h * 64 + db * 16 + l16] =
            (f16)(o[mi][db][r] * rinv[mi][r]);
}

// --------------------------- GEMM2: y @ W_proj (pipelined, R17) -------------
// Same counted-vmcnt structure as k_gemm_qkv; epilogue = direct f32 stores.
// grid (4, 64) = 256 blocks = 1/CU.

__global__ __launch_bounds__(512, 2) void k_gemm_proj(
    const f16* __restrict__ A, const f16* __restrict__ Bt,
    const float* __restrict__ bias, float* __restrict__ out) {
  constexpr int KD = 1024;
  constexpr int SLOT = (128 + 256) * 64;
  __shared__ __align__(16) f16 smem[3 * SLOT];      // 144KB
  const int tid = threadIdx.x;
  const int wave = tid >> 6, lane = tid & 63;
  const int g = lane >> 4, l16 = lane & 15;
  const int m0 = blockIdx.y * 128, n0 = blockIdx.x * 256;
  const int wm = (wave >> 2) * 64, wn = (wave & 3) * 64;
  const int srow = wave * 8 + (lane >> 3);
  const int skc = ((lane & 7) ^ (lane >> 3)) * 8;   // pre-swizzled src chunk

  f32x4 acc[4][4] = {};

  for (int t = 0; t < 2; ++t) {
    f16* Sa = smem + t * SLOT;
    f16* Sb = Sa + 128 * 64;
    for (int it = 0; it < 2; ++it)
      gload_lds16(A + (size_t)(m0 + it * 64 + srow) * KD + t * 64 + skc,
                  Sa + (it * 64 + wave * 8) * 64);
    for (int it = 0; it < 4; ++it)
      gload_lds16(Bt + (size_t)(n0 + it * 64 + srow) * KD + t * 64 + skc,
                  Sb + (it * 64 + wave * 8) * 64);
  }
  asm volatile("s_waitcnt vmcnt(6)" ::: "memory");
  __builtin_amdgcn_s_barrier();

  for (int u = 0; u < 16; ++u) {
    const int s = u % 3;
    f16* Sa = smem + s * SLOT;
    f16* Sb = Sa + 128 * 64;
    const bool pf = (u + 2) < 16;
    f16* Pa = smem + ((u + 2) % 3) * SLOT;
    f16* Pb = Pa + 128 * 64;
    const int kp = (u + 2) * 64;

    for (int kk = 0; kk < 2; ++kk) {
      if (pf) {
        if (kk == 0) {
          gload_lds16(A + (size_t)(m0 + srow) * KD + kp + skc,
                      Pa + (wave * 8) * 64);
          gload_lds16(A + (size_t)(m0 + 64 + srow) * KD + kp + skc,
                      Pa + (64 + wave * 8) * 64);
          gload_lds16(Bt + (size_t)(n0 + srow) * KD + kp + skc,
                      Pb + (wave * 8) * 64);
        } else {
          gload_lds16(Bt + (size_t)(n0 + 64 + srow) * KD + kp + skc,
                      Pb + (64 + wave * 8) * 64);
          gload_lds16(Bt + (size_t)(n0 + 128 + srow) * KD + kp + skc,
                      Pb + (128 + wave * 8) * 64);
          gload_lds16(Bt + (size_t)(n0 + 192 + srow) * KD + kp + skc,
                      Pb + (192 + wave * 8) * 64);
        }
      }

      const int ks = kk * 4;
      f16x8 af[4], bf[4];
      for (int mi = 0; mi < 4; ++mi) {
        int R = wm + mi * 16 + l16, sw = R & 7;
        af[mi] = *(const f16x8*)(Sa + R * 64 + ((ks + g) ^ sw) * 8);
      }
      for (int ni = 0; ni < 4; ++ni) {
        int R = wn + ni * 16 + l16, sw = R & 7;
        bf[ni] = *(const f16x8*)(Sb + R * 64 + ((ks + g) ^ sw) * 8);
      }
      __builtin_amdgcn_s_setprio(1);
      for (int mi = 0; mi < 4; ++mi)
        for (int ni = 0; ni < 4; ++ni)
          acc[mi][ni] = MFMA16x32(af[mi], bf[ni], acc[mi][ni]);
      __builtin_amdgcn_s_setprio(0);
    }

    if (u < 14)
      asm volatile("s_waitcnt vmcnt(6)" ::: "memory");
    else
      asm volatile("s_waitcnt vmcnt(0)" ::: "memory");
    __builtin_amdgcn_s_barrier();
  }

  float bv[4];
  for (int ni = 0; ni < 4; ++ni) bv[ni] = bias[n0 + wn + ni * 16 + l16];

  for (int mi = 0; mi < 4; ++mi)
    for (int ni = 0; ni < 4; ++ni)
      for (int r = 0; r < 4; ++r) {
        int m = m0 + wm + mi * 16 + g * 4 + r;
        int n = n0 + wn + ni * 16 + l16;
        out[(size_t)m * 1024 + n] = acc[mi][ni][r] + bv[ni];
      }
}

// --------------------------- launch ----------------------------------------

extern "C" void kernel_launch(void* const* d_in, const int* in_sizes, int n_in,
                              void* d_out, int out_size, void* d_ws,
                              size_t ws_size, hipStream_t stream) {
  const float* x      = (const float*)d_in[0];
  const float* W_qkv  = (const float*)d_in[1];
  const float* b_qkv  = (const float*)d_in[2];
  const float* W_proj = (const float*)d_in[3];
  const float* b_proj = (const float*)d_in[4];
  float* out = (float*)d_out;

  char* ws = (char*)d_ws;
  f16* xh    = (f16*)ws;   ws += (size_t)8192 * 1024 * 2;   // also reused as Y
  f16* Wqt   = (f16*)ws;   ws += (size_t)3072 * 1024 * 2;
  f16* Wpt   = (f16*)ws;   ws += (size_t)1024 * 1024 * 2;
  f16* Qb    = (f16*)ws;   ws += (size_t)64 * 2048 * 64 * 2;
  f16* Kb    = (f16*)ws;   ws += (size_t)64 * 2048 * 64 * 2;
  f16* Vt    = (f16*)ws;   ws += (size_t)64 * 64 * 2048 * 2;
  f16* Y = xh;  // xh fully consumed by k_gemm_qkv before k_attn writes Y

  k_prep<<<12288, 256, 0, stream>>>(x, xh, W_qkv, Wqt, W_proj, Wpt);
  k_gemm_qkv<<<dim3(12, 64), 512, 0, stream>>>(xh, Wqt, b_qkv, Qb, Kb, Vt);
  k_attn<<<dim3(64, 16), 256, 0, stream>>>(Qb, Kb, Vt, Y);
  k_gemm_proj<<<dim3(4, 64), 512, 0, stream>>>(Y, Wpt, b_proj, out);
}